// Round 1
// baseline (1154.541 us; speedup 1.0000x reference)
//
#include <hip/hip_runtime.h>
#include <hip/hip_bf16.h>

#define DEVI __device__ __forceinline__

using f32x4  = __attribute__((ext_vector_type(4))) float;
using bf16x8 = __attribute__((ext_vector_type(8))) short;
using s16x4  = __attribute__((ext_vector_type(4))) short;

// ---------- bf16 helpers (bit-level, RNE) ----------
DEVI float b2f(unsigned short u) {
  unsigned int x = ((unsigned int)u) << 16;
  return __uint_as_float(x);
}
DEVI unsigned short f2b(float f) {
  unsigned int x = __float_as_uint(f);
  unsigned int r = x + 0x7fffu + ((x >> 16) & 1u);
  return (unsigned short)(r >> 16);
}

// ---------- async global->LDS (16B per lane) ----------
DEVI void gload_lds16(const void* g, void* l) {
  __builtin_amdgcn_global_load_lds(
      (const __attribute__((address_space(1))) void*)g,
      (__attribute__((address_space(3))) void*)l, 16, 0, 0);
}

// ---------- constants ----------
constexpr int kB = 32, kH = 64, kW = 64, kC = 256;
constexpr int kNH = 8, kWS = 8, kSS = 4, kN = 64, kHD = 32;
constexpr int kTOK = kB * kH * kW;        // 131072
constexpr int kMLP = 4 * kC;              // 1024

// =====================================================================
// Weight fp32 -> bf16 convert
// =====================================================================
__global__ void conv_bf16(const float* __restrict__ src,
                          unsigned short* __restrict__ dst, int n4) {
  int i = blockIdx.x * blockDim.x + threadIdx.x;
  if (i < n4) {
    float4 v = *reinterpret_cast<const float4*>(src + (size_t)i * 4);
    s16x4 o;
    o[0] = (short)f2b(v.x); o[1] = (short)f2b(v.y);
    o[2] = (short)f2b(v.z); o[3] = (short)f2b(v.w);
    *reinterpret_cast<s16x4*>(dst + (size_t)i * 4) = o;
  }
}

// =====================================================================
// LN1 + cyclic shift + window partition. One wave per destination token.
// Output: xw [B*nW, N, C] bf16, window-ordered.
// =====================================================================
__global__ __launch_bounds__(256) void ln1_shift_win(
    const float* __restrict__ x, const float* __restrict__ w,
    const float* __restrict__ bb, unsigned short* __restrict__ xw) {
  int wave = threadIdx.x >> 6, lane = threadIdx.x & 63;
  int t_dst = blockIdx.x * 4 + wave;          // window-layout token id
  int widx = t_dst >> 6, tok = t_dst & 63;
  int b = widx >> 6, win = widx & 63;
  int wh = win >> 3, ww = win & 7;
  int y = tok >> 3, xx = tok & 7;
  int r = (wh * 8 + y + kSS) & 63;            // roll(-SS): h[r]=x[(r+SS)%64]
  int c = (ww * 8 + xx + kSS) & 63;
  const float* src = x + ((size_t)b * 4096 + r * 64 + c) * kC;

  float4 v = *reinterpret_cast<const float4*>(src + lane * 4);
  float s  = v.x + v.y + v.z + v.w;
  float s2 = v.x * v.x + v.y * v.y + v.z * v.z + v.w * v.w;
#pragma unroll
  for (int o = 32; o > 0; o >>= 1) {
    s  += __shfl_xor(s, o);
    s2 += __shfl_xor(s2, o);
  }
  float mu = s * (1.f / kC);
  float var = s2 * (1.f / kC) - mu * mu;
  float rstd = rsqrtf(var + 1e-5f);
  float4 wv = *reinterpret_cast<const float4*>(w + lane * 4);
  float4 bv = *reinterpret_cast<const float4*>(bb + lane * 4);
  s16x4 o;
  o[0] = (short)f2b((v.x - mu) * rstd * wv.x + bv.x);
  o[1] = (short)f2b((v.y - mu) * rstd * wv.y + bv.y);
  o[2] = (short)f2b((v.z - mu) * rstd * wv.z + bv.z);
  o[3] = (short)f2b((v.w - mu) * rstd * wv.w + bv.w);
  *reinterpret_cast<s16x4*>(xw + (size_t)t_dst * kC + lane * 4) = o;
}

// =====================================================================
// Generic GEMM: A [M,K] bf16 row-major, Bw [Nc,K] bf16 row-major (= W),
// C = A @ W^T + bias. EPI: 0 none, 1 exact GELU, 2 add residual (fp32 out).
// 128x128 tile, BK=64, 4 waves, 16x16x32 bf16 MFMA.
// =====================================================================
template <int EPI, typename OUT_T>
__global__ __launch_bounds__(256) void gemm_bt(
    const unsigned short* __restrict__ A, const unsigned short* __restrict__ Bw,
    const float* __restrict__ bias, OUT_T* __restrict__ Co,
    const float* __restrict__ res, int M, int Nc, int K) {
  constexpr int BM = 128, BN = 128, BK = 64;
  __shared__ unsigned short sA[BM * BK];
  __shared__ unsigned short sB[BN * BK];
  int tid = threadIdx.x;
  int lane = tid & 63, wave = tid >> 6;
  int nbn = Nc / BN;
  int bm = (blockIdx.x / nbn) * BM;
  int bn = (blockIdx.x % nbn) * BN;
  int wr = wave >> 1, wc = wave & 1;

  f32x4 acc[4][4];
#pragma unroll
  for (int m = 0; m < 4; ++m)
#pragma unroll
    for (int n = 0; n < 4; ++n) acc[m][n] = (f32x4){0.f, 0.f, 0.f, 0.f};

  for (int k0 = 0; k0 < K; k0 += BK) {
#pragma unroll
    for (int it = 0; it < 4; ++it) {
      int c = it * 256 + tid;
      int row = c >> 3;
      int kc = (c & 7) * 8;
      const unsigned short* gA = A + (size_t)(bm + row) * K + k0 + kc;
      const unsigned short* gB = Bw + (size_t)(bn + row) * K + k0 + kc;
      char* lA = (char*)sA + (it * 256 + wave * 64) * 16;
      char* lB = (char*)sB + (it * 256 + wave * 64) * 16;
      gload_lds16(gA, lA);
      gload_lds16(gB, lB);
    }
    __syncthreads();
#pragma unroll
    for (int kk = 0; kk < 2; ++kk) {
      bf16x8 af[4], bfr[4];
#pragma unroll
      for (int m = 0; m < 4; ++m) {
        int row = wr * 64 + m * 16 + (lane & 15);
        af[m] = *reinterpret_cast<const bf16x8*>(
            &sA[row * BK + kk * 32 + (lane >> 4) * 8]);
      }
#pragma unroll
      for (int n = 0; n < 4; ++n) {
        int row = wc * 64 + n * 16 + (lane & 15);
        bfr[n] = *reinterpret_cast<const bf16x8*>(
            &sB[row * BK + kk * 32 + (lane >> 4) * 8]);
      }
#pragma unroll
      for (int m = 0; m < 4; ++m)
#pragma unroll
        for (int n = 0; n < 4; ++n)
          acc[m][n] = __builtin_amdgcn_mfma_f32_16x16x32_bf16(
              af[m], bfr[n], acc[m][n], 0, 0, 0);
    }
    __syncthreads();
  }

  // Epilogue. D layout: row = (lane>>4)*4 + i, col = lane & 15.
#pragma unroll
  for (int m = 0; m < 4; ++m) {
#pragma unroll
    for (int n = 0; n < 4; ++n) {
      int row0 = bm + wr * 64 + m * 16 + ((lane >> 4) << 2);
      int col = bn + wc * 64 + n * 16 + (lane & 15);
      float bcol = bias[col];
#pragma unroll
      for (int i = 0; i < 4; ++i) {
        float v = acc[m][n][i] + bcol;
        size_t idx = (size_t)(row0 + i) * Nc + col;
        if constexpr (EPI == 1) {
          v = 0.5f * v * (1.0f + erff(v * 0.70710678118654752f));
        }
        if constexpr (EPI == 2) {
          v += res[idx];
        }
        if constexpr (sizeof(OUT_T) == 2) {
          Co[idx] = (OUT_T)f2b(v);
        } else {
          Co[idx] = v;
        }
      }
    }
  }
}

// =====================================================================
// Windowed attention: one wave per (window, head). Online softmax.
// qkv: [B*nW, N, 768] bf16 (3*NH*HD channel order). out: [B*nW, N, 256] bf16.
// =====================================================================
__global__ __launch_bounds__(64) void attn_win(
    const unsigned short* __restrict__ qkv, const float* __restrict__ rpb,
    unsigned short* __restrict__ outb) {
  __shared__ float kf[64][33];
  __shared__ float vf[64][33];
  int t = threadIdx.x;
  int widx = blockIdx.x >> 3, h = blockIdx.x & 7;
  int win = widx & 63;
  int wh = win >> 3, ww = win & 7;
  size_t base = ((size_t)widx * 64 + t) * 768;

  const unsigned short* kp = qkv + base + 256 + h * 32;
  const unsigned short* vp = qkv + base + 512 + h * 32;
#pragma unroll
  for (int i = 0; i < 8; ++i) {
    s16x4 k4 = *reinterpret_cast<const s16x4*>(kp + i * 4);
    s16x4 v4 = *reinterpret_cast<const s16x4*>(vp + i * 4);
#pragma unroll
    for (int j = 0; j < 4; ++j) {
      kf[t][i * 4 + j] = b2f((unsigned short)k4[j]);
      vf[t][i * 4 + j] = b2f((unsigned short)v4[j]);
    }
  }
  float q[32];
  const unsigned short* qp = qkv + base + h * 32;
  constexpr float scale = 0.17677669529663687f;  // 32^-0.5
#pragma unroll
  for (int i = 0; i < 8; ++i) {
    s16x4 q4 = *reinterpret_cast<const s16x4*>(qp + i * 4);
#pragma unroll
    for (int j = 0; j < 4; ++j) q[i * 4 + j] = b2f((unsigned short)q4[j]) * scale;
  }
  __syncthreads();

  int yi = t >> 3, xi = t & 7;
  int gyi = wh * 8 + yi, gxi = ww * 8 + xi;
  int ryi = gyi < 56 ? 0 : (gyi < 60 ? 1 : 2);
  int rxi = gxi < 56 ? 0 : (gxi < 60 ? 1 : 2);

  float m = -1e30f, l = 0.f;
  float acc[32];
#pragma unroll
  for (int d = 0; d < 32; ++d) acc[d] = 0.f;

  for (int j = 0; j < 64; ++j) {
    int yj = j >> 3, xj = j & 7;
    float s = rpb[((yi - yj + 7) * 15 + (xi - xj + 7)) * 8 + h];
    int gyj = wh * 8 + yj, gxj = ww * 8 + xj;
    int ryj = gyj < 56 ? 0 : (gyj < 60 ? 1 : 2);
    int rxj = gxj < 56 ? 0 : (gxj < 60 ? 1 : 2);
    if ((ryi != ryj) || (rxi != rxj)) s -= 100.f;
#pragma unroll
    for (int d = 0; d < 32; ++d) s += q[d] * kf[j][d];
    float mn = fmaxf(m, s);
    float sc = __expf(m - mn);
    float p = __expf(s - mn);
    l = l * sc + p;
#pragma unroll
    for (int d = 0; d < 32; ++d) acc[d] = acc[d] * sc + p * vf[j][d];
    m = mn;
  }
  float rl = 1.f / l;
  unsigned short* op = outb + ((size_t)widx * 64 + t) * 256 + h * 32;
#pragma unroll
  for (int i = 0; i < 8; ++i) {
    s16x4 o;
#pragma unroll
    for (int j = 0; j < 4; ++j) o[j] = (short)f2b(acc[i * 4 + j] * rl);
    *reinterpret_cast<s16x4*>(op + i * 4) = o;
  }
}

// =====================================================================
// Residual add (window-reverse + unshift gather) + LN2.
// Writes x1 fp32 into d_out (scratch reuse) and LN2(x1) bf16 for FC1.
// =====================================================================
__global__ __launch_bounds__(256) void resid_ln2(
    const float* __restrict__ x, const unsigned short* __restrict__ proj,
    const float* __restrict__ w2, const float* __restrict__ b2,
    float* __restrict__ x1out, unsigned short* __restrict__ ln2out) {
  int wave = threadIdx.x >> 6, lane = threadIdx.x & 63;
  int t = blockIdx.x * 4 + wave;   // original-layout token
  int b = t >> 12, p = t & 4095;
  int r = p >> 6, c = p & 63;
  int rr = (r + 64 - kSS) & 63;    // roll(+SS): final[r] = h_out[(r-SS)%64]
  int cc = (c + 64 - kSS) & 63;
  int widx = b * 64 + (rr >> 3) * 8 + (cc >> 3);
  int tok = (rr & 7) * 8 + (cc & 7);
  size_t srow = ((size_t)widx * 64 + tok) * 256;

  float4 xv = *reinterpret_cast<const float4*>(x + (size_t)t * kC + lane * 4);
  s16x4 pv = *reinterpret_cast<const s16x4*>(proj + srow + lane * 4);
  float v0 = xv.x + b2f((unsigned short)pv[0]);
  float v1 = xv.y + b2f((unsigned short)pv[1]);
  float v2 = xv.z + b2f((unsigned short)pv[2]);
  float v3 = xv.w + b2f((unsigned short)pv[3]);

  float4 o4; o4.x = v0; o4.y = v1; o4.z = v2; o4.w = v3;
  *reinterpret_cast<float4*>(x1out + (size_t)t * kC + lane * 4) = o4;

  float s = v0 + v1 + v2 + v3;
  float s2 = v0 * v0 + v1 * v1 + v2 * v2 + v3 * v3;
#pragma unroll
  for (int o = 32; o > 0; o >>= 1) {
    s  += __shfl_xor(s, o);
    s2 += __shfl_xor(s2, o);
  }
  float mu = s * (1.f / kC);
  float var = s2 * (1.f / kC) - mu * mu;
  float rstd = rsqrtf(var + 1e-5f);
  float4 wv = *reinterpret_cast<const float4*>(w2 + lane * 4);
  float4 bv = *reinterpret_cast<const float4*>(b2 + lane * 4);
  s16x4 o;
  o[0] = (short)f2b((v0 - mu) * rstd * wv.x + bv.x);
  o[1] = (short)f2b((v1 - mu) * rstd * wv.y + bv.y);
  o[2] = (short)f2b((v2 - mu) * rstd * wv.z + bv.z);
  o[3] = (short)f2b((v3 - mu) * rstd * wv.w + bv.w);
  *reinterpret_cast<s16x4*>(ln2out + (size_t)t * kC + lane * 4) = o;
}

// =====================================================================
extern "C" void kernel_launch(void* const* d_in, const int* in_sizes, int n_in,
                              void* d_out, int out_size, void* d_ws,
                              size_t ws_size, hipStream_t stream) {
  const float* x      = (const float*)d_in[0];
  const float* n1w    = (const float*)d_in[1];
  const float* n1b    = (const float*)d_in[2];
  const float* qkvw   = (const float*)d_in[3];
  const float* qkvb   = (const float*)d_in[4];
  const float* rpb    = (const float*)d_in[5];
  const float* projw  = (const float*)d_in[6];
  const float* projb  = (const float*)d_in[7];
  const float* n2w    = (const float*)d_in[8];
  const float* n2b    = (const float*)d_in[9];
  const float* fc1w   = (const float*)d_in[10];
  const float* fc1b   = (const float*)d_in[11];
  const float* fc2w   = (const float*)d_in[12];
  const float* fc2b   = (const float*)d_in[13];
  float* out = (float*)d_out;

  unsigned short* wq = (unsigned short*)d_ws;          // 768*256
  unsigned short* wp = wq + 768 * 256;                 // 256*256
  unsigned short* w1 = wp + 256 * 256;                 // 1024*256
  unsigned short* w2 = w1 + 1024 * 256;                // 256*1024
  unsigned short* bufA = w2 + 256 * 1024;              // 131072*256 bf16
  unsigned short* bufB = bufA + (size_t)kTOK * kC;     // 131072*1024 bf16

  // weights -> bf16
  conv_bf16<<<192, 256, 0, stream>>>(qkvw, wq, 49152);
  conv_bf16<<<64, 256, 0, stream>>>(projw, wp, 16384);
  conv_bf16<<<256, 256, 0, stream>>>(fc1w, w1, 65536);
  conv_bf16<<<256, 256, 0, stream>>>(fc2w, w2, 65536);

  // LN1 + shift + window partition
  ln1_shift_win<<<kTOK / 4, 256, 0, stream>>>(x, n1w, n1b, bufA);

  // QKV GEMM: [131072,256] x [768,256]^T -> bufB
  gemm_bt<0, unsigned short><<<(kTOK / 128) * (768 / 128), 256, 0, stream>>>(
      bufA, wq, qkvb, bufB, nullptr, kTOK, 768, kC);

  // attention -> bufA
  attn_win<<<(kTOK / 64) * kNH, 64, 0, stream>>>(bufB, rpb, bufA);

  // proj GEMM: -> bufB (qkv dead)
  gemm_bt<0, unsigned short><<<(kTOK / 128) * (kC / 128), 256, 0, stream>>>(
      bufA, wp, projb, bufB, nullptr, kTOK, kC, kC);

  // residual + LN2: x1 -> d_out, ln2 -> bufA
  resid_ln2<<<kTOK / 4, 256, 0, stream>>>(x, bufB, n2w, n2b, out, bufA);

  // FC1 + GELU: [131072,256] x [1024,256]^T -> bufB
  gemm_bt<1, unsigned short><<<(kTOK / 128) * (kMLP / 128), 256, 0, stream>>>(
      bufA, w1, fc1b, bufB, nullptr, kTOK, kMLP, kC);

  // FC2 + residual: [131072,1024] x [256,1024]^T + x1 -> d_out
  gemm_bt<2, float><<<(kTOK / 128) * (kC / 128), 256, 0, stream>>>(
      bufB, w2, fc2b, out, out, kTOK, kC, kMLP);
}

// Round 3
// 990.690 us; speedup vs baseline: 1.1654x; 1.1654x over previous
//
#include <hip/hip_runtime.h>
#include <hip/hip_bf16.h>

#define DEVI __device__ __forceinline__

using f32x4  = __attribute__((ext_vector_type(4))) float;
using bf16x8 = __attribute__((ext_vector_type(8))) short;
using s16x4  = __attribute__((ext_vector_type(4))) short;

// ---------- bf16 helpers (bit-level, RNE) ----------
DEVI float b2f(unsigned short u) {
  unsigned int x = ((unsigned int)u) << 16;
  return __uint_as_float(x);
}
DEVI unsigned short f2b(float f) {
  unsigned int x = __float_as_uint(f);
  unsigned int r = x + 0x7fffu + ((x >> 16) & 1u);
  return (unsigned short)(r >> 16);
}

// ---------- async global->LDS (16B per lane) ----------
DEVI void gload_lds16(const void* g, void* l) {
  __builtin_amdgcn_global_load_lds(
      (const __attribute__((address_space(1))) void*)g,
      (__attribute__((address_space(3))) void*)l, 16, 0, 0);
}

// ---------- constants ----------
constexpr int kB = 32, kH = 64, kW = 64, kC = 256;
constexpr int kNH = 8, kWS = 8, kSS = 4, kN = 64, kHD = 32;
constexpr int kTOK = kB * kH * kW;        // 131072
constexpr int kMLP = 4 * kC;              // 1024

// =====================================================================
// Weight fp32 -> bf16 convert
// =====================================================================
__global__ void conv_bf16(const float* __restrict__ src,
                          unsigned short* __restrict__ dst, int n4) {
  int i = blockIdx.x * blockDim.x + threadIdx.x;
  if (i < n4) {
    float4 v = *reinterpret_cast<const float4*>(src + (size_t)i * 4);
    s16x4 o;
    o[0] = (short)f2b(v.x); o[1] = (short)f2b(v.y);
    o[2] = (short)f2b(v.z); o[3] = (short)f2b(v.w);
    *reinterpret_cast<s16x4*>(dst + (size_t)i * 4) = o;
  }
}

// =====================================================================
// LN1 + cyclic shift + window partition. One wave per destination token.
// =====================================================================
__global__ __launch_bounds__(256) void ln1_shift_win(
    const float* __restrict__ x, const float* __restrict__ w,
    const float* __restrict__ bb, unsigned short* __restrict__ xw) {
  int wave = threadIdx.x >> 6, lane = threadIdx.x & 63;
  int t_dst = blockIdx.x * 4 + wave;
  int widx = t_dst >> 6, tok = t_dst & 63;
  int b = widx >> 6, win = widx & 63;
  int wh = win >> 3, ww = win & 7;
  int y = tok >> 3, xx = tok & 7;
  int r = (wh * 8 + y + kSS) & 63;
  int c = (ww * 8 + xx + kSS) & 63;
  const float* src = x + ((size_t)b * 4096 + r * 64 + c) * kC;

  float4 v = *reinterpret_cast<const float4*>(src + lane * 4);
  float s  = v.x + v.y + v.z + v.w;
  float s2 = v.x * v.x + v.y * v.y + v.z * v.z + v.w * v.w;
#pragma unroll
  for (int o = 32; o > 0; o >>= 1) {
    s  += __shfl_xor(s, o);
    s2 += __shfl_xor(s2, o);
  }
  float mu = s * (1.f / kC);
  float var = s2 * (1.f / kC) - mu * mu;
  float rstd = rsqrtf(var + 1e-5f);
  float4 wv = *reinterpret_cast<const float4*>(w + lane * 4);
  float4 bv = *reinterpret_cast<const float4*>(bb + lane * 4);
  s16x4 o;
  o[0] = (short)f2b((v.x - mu) * rstd * wv.x + bv.x);
  o[1] = (short)f2b((v.y - mu) * rstd * wv.y + bv.y);
  o[2] = (short)f2b((v.z - mu) * rstd * wv.z + bv.z);
  o[3] = (short)f2b((v.w - mu) * rstd * wv.w + bv.w);
  *reinterpret_cast<s16x4*>(xw + (size_t)t_dst * kC + lane * 4) = o;
}

// =====================================================================
// Generic GEMM (128x128 tile, BK=64, 4 waves, 16x16x32 bf16 MFMA).
// =====================================================================
template <int EPI, typename OUT_T>
__global__ __launch_bounds__(256) void gemm_bt(
    const unsigned short* __restrict__ A, const unsigned short* __restrict__ Bw,
    const float* __restrict__ bias, OUT_T* __restrict__ Co,
    const float* __restrict__ res, int M, int Nc, int K) {
  constexpr int BM = 128, BN = 128, BK = 64;
  __shared__ unsigned short sA[BM * BK];
  __shared__ unsigned short sB[BN * BK];
  int tid = threadIdx.x;
  int lane = tid & 63, wave = tid >> 6;
  int nbn = Nc / BN;
  int bm = (blockIdx.x / nbn) * BM;
  int bn = (blockIdx.x % nbn) * BN;
  int wr = wave >> 1, wc = wave & 1;

  f32x4 acc[4][4];
#pragma unroll
  for (int m = 0; m < 4; ++m)
#pragma unroll
    for (int n = 0; n < 4; ++n) acc[m][n] = (f32x4){0.f, 0.f, 0.f, 0.f};

  for (int k0 = 0; k0 < K; k0 += BK) {
#pragma unroll
    for (int it = 0; it < 4; ++it) {
      int c = it * 256 + tid;
      int row = c >> 3;
      int kc = (c & 7) * 8;
      const unsigned short* gA = A + (size_t)(bm + row) * K + k0 + kc;
      const unsigned short* gB = Bw + (size_t)(bn + row) * K + k0 + kc;
      char* lA = (char*)sA + (it * 256 + wave * 64) * 16;
      char* lB = (char*)sB + (it * 256 + wave * 64) * 16;
      gload_lds16(gA, lA);
      gload_lds16(gB, lB);
    }
    __syncthreads();
#pragma unroll
    for (int kk = 0; kk < 2; ++kk) {
      bf16x8 af[4], bfr[4];
#pragma unroll
      for (int m = 0; m < 4; ++m) {
        int row = wr * 64 + m * 16 + (lane & 15);
        af[m] = *reinterpret_cast<const bf16x8*>(
            &sA[row * BK + kk * 32 + (lane >> 4) * 8]);
      }
#pragma unroll
      for (int n = 0; n < 4; ++n) {
        int row = wc * 64 + n * 16 + (lane & 15);
        bfr[n] = *reinterpret_cast<const bf16x8*>(
            &sB[row * BK + kk * 32 + (lane >> 4) * 8]);
      }
#pragma unroll
      for (int m = 0; m < 4; ++m)
#pragma unroll
        for (int n = 0; n < 4; ++n)
          acc[m][n] = __builtin_amdgcn_mfma_f32_16x16x32_bf16(
              af[m], bfr[n], acc[m][n], 0, 0, 0);
    }
    __syncthreads();
  }

#pragma unroll
  for (int m = 0; m < 4; ++m) {
#pragma unroll
    for (int n = 0; n < 4; ++n) {
      int row0 = bm + wr * 64 + m * 16 + ((lane >> 4) << 2);
      int col = bn + wc * 64 + n * 16 + (lane & 15);
      float bcol = bias[col];
#pragma unroll
      for (int i = 0; i < 4; ++i) {
        float v = acc[m][n][i] + bcol;
        size_t idx = (size_t)(row0 + i) * Nc + col;
        if constexpr (EPI == 1) {
          v = 0.5f * v * (1.0f + erff(v * 0.70710678118654752f));
        }
        if constexpr (EPI == 2) {
          v += res[idx];
        }
        if constexpr (sizeof(OUT_T) == 2) {
          Co[idx] = (OUT_T)f2b(v);
        } else {
          Co[idx] = v;
        }
      }
    }
  }
}

// =====================================================================
// MFMA windowed attention. One wave per window, loops 8 heads.
// Per-wave LDS: P [64][72] bf16, VT [32][72] bf16 (stride 72 keeps b128
// reads 16B-aligned; VT writes 2 lanes/bank).
// qkv: [B*nW, N, 768] bf16 -> out: [B*nW, N, 256] bf16.
// =====================================================================
__global__ __launch_bounds__(128) void attn_mfma(
    const unsigned short* __restrict__ qkv, const float* __restrict__ rpb,
    unsigned short* __restrict__ outb) {
  constexpr int PS = 72;
  __shared__ unsigned short lds[2][(64 + 32) * PS];
  int lane = threadIdx.x & 63, wave = threadIdx.x >> 6;
  int widx = blockIdx.x * 2 + wave;
  int win = widx & 63;
  int wh = win >> 3, ww = win & 7;
  unsigned short* P  = lds[wave];
  unsigned short* VT = lds[wave] + 64 * PS;
  int l15 = lane & 15, g = lane >> 4;
  int gh = g >> 1;                  // (4g+i)>>3 for i<4
  size_t wbase = (size_t)widx * 64 * 768;
  constexpr float scale = 0.17677669529663687f;  // 32^-0.5

  // key-side (column) region data: col = n*16 + l15
  int xj = l15 & 7;
  int gxj = ww * 8 + xj;
  int rxj = gxj < 56 ? 0 : (gxj < 60 ? 1 : 2);
  int yj_[4], ryj_[4];
#pragma unroll
  for (int n = 0; n < 4; ++n) {
    yj_[n] = 2 * n + (l15 >> 3);
    int gyj = wh * 8 + yj_[n];
    ryj_[n] = gyj < 56 ? 0 : (gyj < 60 ? 1 : 2);
  }
  // query-side x data: xi = (g&1)*4 + i
  int rxok_[4], dx8_[4];
#pragma unroll
  for (int i = 0; i < 4; ++i) {
    int xi = (g & 1) * 4 + i;
    int gxi = ww * 8 + xi;
    int rxi = gxi < 56 ? 0 : (gxi < 60 ? 1 : 2);
    rxok_[i] = (rxi == rxj);
    dx8_[i] = (xi - xj + 7) * 8;
  }

  for (int h = 0; h < 8; ++h) {
    const unsigned short* qb = qkv + wbase + h * 32;
    bf16x8 qf[4], kf[4];
#pragma unroll
    for (int m = 0; m < 4; ++m)
      qf[m] = *reinterpret_cast<const bf16x8*>(qb + (size_t)(16 * m + l15) * 768 + g * 8);
#pragma unroll
    for (int n = 0; n < 4; ++n)
      kf[n] = *reinterpret_cast<const bf16x8*>(qb + 256 + (size_t)(16 * n + l15) * 768 + g * 8);

    f32x4 S[4][4];
#pragma unroll
    for (int m = 0; m < 4; ++m)
#pragma unroll
      for (int n = 0; n < 4; ++n) S[m][n] = (f32x4){0.f, 0.f, 0.f, 0.f};
#pragma unroll
    for (int m = 0; m < 4; ++m)
#pragma unroll
      for (int n = 0; n < 4; ++n)
        S[m][n] = __builtin_amdgcn_mfma_f32_16x16x32_bf16(qf[m], kf[n], S[m][n], 0, 0, 0);

    // stage V^T: lane holds V row `lane` (32 dims)
    bf16x8 vrow[4];
#pragma unroll
    for (int i2 = 0; i2 < 4; ++i2)
      vrow[i2] = *reinterpret_cast<const bf16x8*>(qb + 512 + (size_t)lane * 768 + i2 * 8);
#pragma unroll
    for (int i2 = 0; i2 < 4; ++i2)
#pragma unroll
      for (int j = 0; j < 8; ++j)
        VT[(i2 * 8 + j) * PS + lane] = (unsigned short)vrow[i2][j];

    // scale + bias + mask + softmax; write P (bf16) to LDS
#pragma unroll
    for (int m = 0; m < 4; ++m) {
      int yi = 2 * m + gh;
      int gyi = wh * 8 + yi;
      int ryi = gyi < 56 ? 0 : (gyi < 60 ? 1 : 2);
      int dy120_[4], rok_[4];
#pragma unroll
      for (int n = 0; n < 4; ++n) {
        dy120_[n] = (yi - yj_[n] + 7) * 120;
        rok_[n] = (ryi == ryj_[n]);
      }
#pragma unroll
      for (int i = 0; i < 4; ++i) {
        float t[4];
#pragma unroll
        for (int n = 0; n < 4; ++n) {
          float bias = rpb[dy120_[n] + dx8_[i] + h];
          float msk = (rok_[n] && rxok_[i]) ? 0.f : -100.f;
          t[n] = fmaf(S[m][n][i], scale, bias + msk);
        }
        float mx = fmaxf(fmaxf(t[0], t[1]), fmaxf(t[2], t[3]));
#pragma unroll
        for (int o = 1; o < 16; o <<= 1) mx = fmaxf(mx, __shfl_xor(mx, o));
        float sm = 0.f;
#pragma unroll
        for (int n = 0; n < 4; ++n) {
          t[n] = __expf(t[n] - mx);
          sm += t[n];
        }
#pragma unroll
        for (int o = 1; o < 16; o <<= 1) sm += __shfl_xor(sm, o);
        float rl = 1.f / sm;
        int rowoff = (16 * m + 4 * g + i) * PS;
#pragma unroll
        for (int n = 0; n < 4; ++n)
          P[rowoff + 16 * n + l15] = f2b(t[n] * rl);
      }
    }

    // PV: out[q][d] = sum_k P[q][k] * VT[d][k]
    f32x4 O[4][2];
#pragma unroll
    for (int m = 0; m < 4; ++m)
#pragma unroll
      for (int n2 = 0; n2 < 2; ++n2) O[m][n2] = (f32x4){0.f, 0.f, 0.f, 0.f};
#pragma unroll
    for (int kk = 0; kk < 2; ++kk) {
      bf16x8 pa[4], vb[2];
#pragma unroll
      for (int m = 0; m < 4; ++m)
        pa[m] = *reinterpret_cast<const bf16x8*>(&P[(16 * m + l15) * PS + kk * 32 + g * 8]);
#pragma unroll
      for (int n2 = 0; n2 < 2; ++n2)
        vb[n2] = *reinterpret_cast<const bf16x8*>(&VT[(16 * n2 + l15) * PS + kk * 32 + g * 8]);
#pragma unroll
      for (int m = 0; m < 4; ++m)
#pragma unroll
        for (int n2 = 0; n2 < 2; ++n2)
          O[m][n2] = __builtin_amdgcn_mfma_f32_16x16x32_bf16(pa[m], vb[n2], O[m][n2], 0, 0, 0);
    }

    unsigned short* ob = outb + (size_t)widx * 64 * 256 + h * 32;
#pragma unroll
    for (int m = 0; m < 4; ++m)
#pragma unroll
      for (int n2 = 0; n2 < 2; ++n2)
#pragma unroll
        for (int i = 0; i < 4; ++i)
          ob[(16 * m + 4 * g + i) * 256 + 16 * n2 + l15] = f2b(O[m][n2][i]);
  }
}

// =====================================================================
// Residual add (window-reverse + unshift gather) + LN2.
// =====================================================================
__global__ __launch_bounds__(256) void resid_ln2(
    const float* __restrict__ x, const unsigned short* __restrict__ proj,
    const float* __restrict__ w2, const float* __restrict__ b2,
    float* __restrict__ x1out, unsigned short* __restrict__ ln2out) {
  int wave = threadIdx.x >> 6, lane = threadIdx.x & 63;
  int t = blockIdx.x * 4 + wave;
  int b = t >> 12, p = t & 4095;
  int r = p >> 6, c = p & 63;
  int rr = (r + 64 - kSS) & 63;
  int cc = (c + 64 - kSS) & 63;
  int widx = b * 64 + (rr >> 3) * 8 + (cc >> 3);
  int tok = (rr & 7) * 8 + (cc & 7);
  size_t srow = ((size_t)widx * 64 + tok) * 256;

  float4 xv = *reinterpret_cast<const float4*>(x + (size_t)t * kC + lane * 4);
  s16x4 pv = *reinterpret_cast<const s16x4*>(proj + srow + lane * 4);
  float v0 = xv.x + b2f((unsigned short)pv[0]);
  float v1 = xv.y + b2f((unsigned short)pv[1]);
  float v2 = xv.z + b2f((unsigned short)pv[2]);
  float v3 = xv.w + b2f((unsigned short)pv[3]);

  float4 o4; o4.x = v0; o4.y = v1; o4.z = v2; o4.w = v3;
  *reinterpret_cast<float4*>(x1out + (size_t)t * kC + lane * 4) = o4;

  float s = v0 + v1 + v2 + v3;
  float s2 = v0 * v0 + v1 * v1 + v2 * v2 + v3 * v3;
#pragma unroll
  for (int o = 32; o > 0; o >>= 1) {
    s  += __shfl_xor(s, o);
    s2 += __shfl_xor(s2, o);
  }
  float mu = s * (1.f / kC);
  float var = s2 * (1.f / kC) - mu * mu;
  float rstd = rsqrtf(var + 1e-5f);
  float4 wv = *reinterpret_cast<const float4*>(w2 + lane * 4);
  float4 bv = *reinterpret_cast<const float4*>(b2 + lane * 4);
  s16x4 o;
  o[0] = (short)f2b((v0 - mu) * rstd * wv.x + bv.x);
  o[1] = (short)f2b((v1 - mu) * rstd * wv.y + bv.y);
  o[2] = (short)f2b((v2 - mu) * rstd * wv.z + bv.z);
  o[3] = (short)f2b((v3 - mu) * rstd * wv.w + bv.w);
  *reinterpret_cast<s16x4*>(ln2out + (size_t)t * kC + lane * 4) = o;
}

// =====================================================================
extern "C" void kernel_launch(void* const* d_in, const int* in_sizes, int n_in,
                              void* d_out, int out_size, void* d_ws,
                              size_t ws_size, hipStream_t stream) {
  const float* x      = (const float*)d_in[0];
  const float* n1w    = (const float*)d_in[1];
  const float* n1b    = (const float*)d_in[2];
  const float* qkvw   = (const float*)d_in[3];
  const float* qkvb   = (const float*)d_in[4];
  const float* rpb    = (const float*)d_in[5];
  const float* projw  = (const float*)d_in[6];
  const float* projb  = (const float*)d_in[7];
  const float* n2w    = (const float*)d_in[8];
  const float* n2b    = (const float*)d_in[9];
  const float* fc1w   = (const float*)d_in[10];
  const float* fc1b   = (const float*)d_in[11];
  const float* fc2w   = (const float*)d_in[12];
  const float* fc2b   = (const float*)d_in[13];
  float* out = (float*)d_out;

  unsigned short* wq = (unsigned short*)d_ws;          // 768*256
  unsigned short* wp = wq + 768 * 256;                 // 256*256
  unsigned short* w1 = wp + 256 * 256;                 // 1024*256
  unsigned short* w2 = w1 + 1024 * 256;                // 256*1024
  unsigned short* bufA = w2 + 256 * 1024;              // 131072*256 bf16
  unsigned short* bufB = bufA + (size_t)kTOK * kC;     // 131072*1024 bf16

  // weights -> bf16
  conv_bf16<<<192, 256, 0, stream>>>(qkvw, wq, 49152);
  conv_bf16<<<64, 256, 0, stream>>>(projw, wp, 16384);
  conv_bf16<<<256, 256, 0, stream>>>(fc1w, w1, 65536);
  conv_bf16<<<256, 256, 0, stream>>>(fc2w, w2, 65536);

  // LN1 + shift + window partition
  ln1_shift_win<<<kTOK / 4, 256, 0, stream>>>(x, n1w, n1b, bufA);

  // QKV GEMM: [131072,256] x [768,256]^T -> bufB
  gemm_bt<0, unsigned short><<<(kTOK / 128) * (768 / 128), 256, 0, stream>>>(
      bufA, wq, qkvb, bufB, nullptr, kTOK, 768, kC);

  // attention -> bufA
  attn_mfma<<<(kTOK / 64) / 2, 128, 0, stream>>>(bufB, rpb, bufA);

  // proj GEMM: -> bufB (qkv dead)
  gemm_bt<0, unsigned short><<<(kTOK / 128) * (kC / 128), 256, 0, stream>>>(
      bufA, wp, projb, bufB, nullptr, kTOK, kC, kC);

  // residual + LN2: x1 -> d_out, ln2 -> bufA
  resid_ln2<<<kTOK / 4, 256, 0, stream>>>(x, bufB, n2w, n2b, out, bufA);

  // FC1 + GELU: [131072,256] x [1024,256]^T -> bufB
  gemm_bt<1, unsigned short><<<(kTOK / 128) * (kMLP / 128), 256, 0, stream>>>(
      bufA, w1, fc1b, bufB, nullptr, kTOK, kMLP, kC);

  // FC2 + residual: [131072,1024] x [256,1024]^T + x1 -> d_out
  gemm_bt<2, float><<<(kTOK / 128) * (kC / 128), 256, 0, stream>>>(
      bufB, w2, fc2b, out, out, kTOK, kC, kMLP);
}

// Round 7
// 935.571 us; speedup vs baseline: 1.2341x; 1.0589x over previous
//
#include <hip/hip_runtime.h>
#include <hip/hip_bf16.h>

#define DEVI __device__ __forceinline__

using f32x4  = __attribute__((ext_vector_type(4))) float;
using bf16x8 = __attribute__((ext_vector_type(8))) short;
using s16x4  = __attribute__((ext_vector_type(4))) short;

// ---------- bf16 helpers (bit-level, RNE) ----------
DEVI float b2f(unsigned short u) {
  unsigned int x = ((unsigned int)u) << 16;
  return __uint_as_float(x);
}
DEVI unsigned short f2b(float f) {
  unsigned int x = __float_as_uint(f);
  unsigned int r = x + 0x7fffu + ((x >> 16) & 1u);
  return (unsigned short)(r >> 16);
}

// ---------- async global->LDS (16B per lane) ----------
DEVI void gload_lds16(const void* g, void* l) {
  __builtin_amdgcn_global_load_lds(
      (const __attribute__((address_space(1))) void*)g,
      (__attribute__((address_space(3))) void*)l, 16, 0, 0);
}

// ---------- constants ----------
constexpr int kB = 32, kH = 64, kW = 64, kC = 256;
constexpr int kNH = 8, kWS = 8, kSS = 4, kN = 64, kHD = 32;
constexpr int kTOK = kB * kH * kW;        // 131072
constexpr int kMLP = 4 * kC;              // 1024

// =====================================================================
// Weight fp32 -> bf16 convert
// =====================================================================
__global__ void conv_bf16(const float* __restrict__ src,
                          unsigned short* __restrict__ dst, int n4) {
  int i = blockIdx.x * blockDim.x + threadIdx.x;
  if (i < n4) {
    float4 v = *reinterpret_cast<const float4*>(src + (size_t)i * 4);
    s16x4 o;
    o[0] = (short)f2b(v.x); o[1] = (short)f2b(v.y);
    o[2] = (short)f2b(v.z); o[3] = (short)f2b(v.w);
    *reinterpret_cast<s16x4*>(dst + (size_t)i * 4) = o;
  }
}

// =====================================================================
// LN1 + cyclic shift + window partition. One wave per destination token.
// =====================================================================
__global__ __launch_bounds__(256) void ln1_shift_win(
    const float* __restrict__ x, const float* __restrict__ w,
    const float* __restrict__ bb, unsigned short* __restrict__ xw) {
  int wave = threadIdx.x >> 6, lane = threadIdx.x & 63;
  int t_dst = blockIdx.x * 4 + wave;
  int widx = t_dst >> 6, tok = t_dst & 63;
  int b = widx >> 6, win = widx & 63;
  int wh = win >> 3, ww = win & 7;
  int y = tok >> 3, xx = tok & 7;
  int r = (wh * 8 + y + kSS) & 63;
  int c = (ww * 8 + xx + kSS) & 63;
  const float* src = x + ((size_t)b * 4096 + r * 64 + c) * kC;

  float4 v = *reinterpret_cast<const float4*>(src + lane * 4);
  float s  = v.x + v.y + v.z + v.w;
  float s2 = v.x * v.x + v.y * v.y + v.z * v.z + v.w * v.w;
#pragma unroll
  for (int o = 32; o > 0; o >>= 1) {
    s  += __shfl_xor(s, o);
    s2 += __shfl_xor(s2, o);
  }
  float mu = s * (1.f / kC);
  float var = s2 * (1.f / kC) - mu * mu;
  float rstd = rsqrtf(var + 1e-5f);
  float4 wv = *reinterpret_cast<const float4*>(w + lane * 4);
  float4 bv = *reinterpret_cast<const float4*>(bb + lane * 4);
  s16x4 o;
  o[0] = (short)f2b((v.x - mu) * rstd * wv.x + bv.x);
  o[1] = (short)f2b((v.y - mu) * rstd * wv.y + bv.y);
  o[2] = (short)f2b((v.z - mu) * rstd * wv.z + bv.z);
  o[3] = (short)f2b((v.w - mu) * rstd * wv.w + bv.w);
  *reinterpret_cast<s16x4*>(xw + (size_t)t_dst * kC + lane * 4) = o;
}

// =====================================================================
// GEMM v2: 512 threads (8 waves, 2x4), BM=128, BN=256, BK=64.
// A [M,K] bf16 row-major, Bw [Nc,K] bf16 row-major; C = A@W^T + bias.
// EPI 0: bias, bf16 out (QKV)
// EPI 1: bias + exact GELU, bf16 out (FC1)
// EPI 3: proj fused: +bias, gather x residual -> x1 (fp32 scatter to gx1,
//        original layout), LN2 -> Co bf16 IN PLACE (window layout; requires
//        Nc==256 so each block owns its A rows exclusively).
// EPI 4: FC2 fused: +bias, gather x1 residual, scatter fp32 out (original
//        layout). Requires Nc==256.
// XCD-chunked block swizzle (grid must be %8==0).
// =====================================================================
template <int EPI, typename OUT_T>
__global__ __launch_bounds__(512, 4) void gemm_bt2(
    const unsigned short* A, const unsigned short* __restrict__ Bw,
    const float* __restrict__ bias, OUT_T* Co,
    const float* xres, float* gx1,
    const float* __restrict__ lnw, const float* __restrict__ lnb,
    int M, int Nc, int K) {
  constexpr int BM = 128, BN = 256, BK = 64;
  __shared__ unsigned short sA[BM * BK];        // 16 KB
  __shared__ unsigned short sB[BN * BK];        // 32 KB
  __shared__ float redS[4][BM], redS2[4][BM];   // 4 KB (EPI3 only)
  int tid = threadIdx.x;
  int lane = tid & 63, wave = tid >> 6;
  int l15 = lane & 15, g = lane >> 4;
  int nbn = Nc / BN;
  int qch = gridDim.x >> 3;                     // blocks per XCD chunk
  int logical = (blockIdx.x & 7) * qch + (blockIdx.x >> 3);
  int bm = (logical / nbn) * BM;
  int bn = (logical % nbn) * BN;
  int wr = wave >> 2, wc = wave & 3;

  f32x4 acc[4][4];
#pragma unroll
  for (int m = 0; m < 4; ++m)
#pragma unroll
    for (int n = 0; n < 4; ++n) acc[m][n] = (f32x4){0.f, 0.f, 0.f, 0.f};

  for (int k0 = 0; k0 < K; k0 += BK) {
#pragma unroll
    for (int it = 0; it < 2; ++it) {
      int c = it * 512 + tid;
      int row = c >> 3, kc = (c & 7) * 8;
      gload_lds16(A + (size_t)(bm + row) * K + k0 + kc,
                  (char*)sA + (it * 512 + wave * 64) * 16);
    }
#pragma unroll
    for (int it = 0; it < 4; ++it) {
      int c = it * 512 + tid;
      int row = c >> 3, kc = (c & 7) * 8;
      gload_lds16(Bw + (size_t)(bn + row) * K + k0 + kc,
                  (char*)sB + (it * 512 + wave * 64) * 16);
    }
    __syncthreads();
#pragma unroll
    for (int kk = 0; kk < 2; ++kk) {
      bf16x8 af[4], bfr[4];
#pragma unroll
      for (int m = 0; m < 4; ++m)
        af[m] = *reinterpret_cast<const bf16x8*>(
            &sA[(wr * 64 + m * 16 + l15) * BK + kk * 32 + g * 8]);
#pragma unroll
      for (int n = 0; n < 4; ++n)
        bfr[n] = *reinterpret_cast<const bf16x8*>(
            &sB[(wc * 64 + n * 16 + l15) * BK + kk * 32 + g * 8]);
#pragma unroll
      for (int m = 0; m < 4; ++m)
#pragma unroll
        for (int n = 0; n < 4; ++n)
          acc[m][n] = __builtin_amdgcn_mfma_f32_16x16x32_bf16(
              af[m], bfr[n], acc[m][n], 0, 0, 0);
    }
    __syncthreads();
  }

  // ---------------- epilogues ----------------
  // D layout: row = (lane>>4)*4 + i, col = lane & 15.
  if constexpr (EPI == 0 || EPI == 1) {
#pragma unroll
    for (int m = 0; m < 4; ++m) {
#pragma unroll
      for (int n = 0; n < 4; ++n) {
        int row0 = bm + wr * 64 + m * 16 + g * 4;
        int col = bn + wc * 64 + n * 16 + l15;
        float bcol = bias[col];
#pragma unroll
        for (int i = 0; i < 4; ++i) {
          float v = acc[m][n][i] + bcol;
          if constexpr (EPI == 1)
            v = 0.5f * v * (1.0f + erff(v * 0.70710678118654752f));
          Co[(size_t)(row0 + i) * Nc + col] = (OUT_T)f2b(v);
        }
      }
    }
  }
  if constexpr (EPI == 3) {
    // window row -> original token: rr=(win>>3)*8+(tok>>3), cc=(win&7)*8+(tok&7)
    // r=(rr+SS)&63, c=(cc+SS)&63  (same mapping ln1 uses for its source)
#pragma unroll
    for (int m = 0; m < 4; ++m) {
#pragma unroll
      for (int i = 0; i < 4; ++i) {
        int row_local = wr * 64 + m * 16 + g * 4 + i;
        int trow = bm + row_local;
        int widx = trow >> 6, tok = trow & 63;
        int b = widx >> 6, win = widx & 63;
        int rr = ((win >> 3) << 3) | (tok >> 3);
        int cc = ((win & 7) << 3) | (tok & 7);
        int r = (rr + kSS) & 63, c2 = (cc + kSS) & 63;
        size_t orow = ((size_t)(b << 12) + (r << 6) + c2) * 256;
        float rs = 0.f, rs2 = 0.f;
#pragma unroll
        for (int n = 0; n < 4; ++n) {
          int col = wc * 64 + n * 16 + l15;
          float v = acc[m][n][i] + bias[col] + xres[orow + col];
          acc[m][n][i] = v;
          gx1[orow + col] = v;
          rs += v; rs2 += v * v;
        }
#pragma unroll
        for (int o = 1; o < 16; o <<= 1) {
          rs  += __shfl_xor(rs, o);
          rs2 += __shfl_xor(rs2, o);
        }
        if (l15 == 0) { redS[wc][row_local] = rs; redS2[wc][row_local] = rs2; }
      }
    }
    __syncthreads();
#pragma unroll
    for (int m = 0; m < 4; ++m) {
#pragma unroll
      for (int i = 0; i < 4; ++i) {
        int row_local = wr * 64 + m * 16 + g * 4 + i;
        int trow = bm + row_local;
        float s  = redS[0][row_local] + redS[1][row_local] +
                   redS[2][row_local] + redS[3][row_local];
        float s2 = redS2[0][row_local] + redS2[1][row_local] +
                   redS2[2][row_local] + redS2[3][row_local];
        float mu = s * (1.f / 256.f);
        float var = s2 * (1.f / 256.f) - mu * mu;
        float rstd = rsqrtf(var + 1e-5f);
#pragma unroll
        for (int n = 0; n < 4; ++n) {
          int col = wc * 64 + n * 16 + l15;
          Co[(size_t)trow * 256 + col] =
              (OUT_T)f2b((acc[m][n][i] - mu) * rstd * lnw[col] + lnb[col]);
        }
      }
    }
  }
  if constexpr (EPI == 4) {
#pragma unroll
    for (int m = 0; m < 4; ++m) {
#pragma unroll
      for (int i = 0; i < 4; ++i) {
        int row_local = wr * 64 + m * 16 + g * 4 + i;
        int trow = bm + row_local;
        int widx = trow >> 6, tok = trow & 63;
        int b = widx >> 6, win = widx & 63;
        int rr = ((win >> 3) << 3) | (tok >> 3);
        int cc = ((win & 7) << 3) | (tok & 7);
        int r = (rr + kSS) & 63, c2 = (cc + kSS) & 63;
        size_t orow = ((size_t)(b << 12) + (r << 6) + c2) * 256;
#pragma unroll
        for (int n = 0; n < 4; ++n) {
          int col = wc * 64 + n * 16 + l15;
          float v = acc[m][n][i] + bias[col] + xres[orow + col];
          Co[orow + col] = v;
        }
      }
    }
  }
}

// =====================================================================
// MFMA windowed attention. One wave per window, loops 8 heads.
// =====================================================================
__global__ __launch_bounds__(128) void attn_mfma(
    const unsigned short* __restrict__ qkv, const float* __restrict__ rpb,
    unsigned short* __restrict__ outb) {
  constexpr int PS = 72;
  __shared__ unsigned short lds[2][(64 + 32) * PS];
  int lane = threadIdx.x & 63, wave = threadIdx.x >> 6;
  int widx = blockIdx.x * 2 + wave;
  int win = widx & 63;
  int wh = win >> 3, ww = win & 7;
  unsigned short* P  = lds[wave];
  unsigned short* VT = lds[wave] + 64 * PS;
  int l15 = lane & 15, g = lane >> 4;
  int gh = g >> 1;
  size_t wbase = (size_t)widx * 64 * 768;
  constexpr float scale = 0.17677669529663687f;  // 32^-0.5

  int xj = l15 & 7;
  int gxj = ww * 8 + xj;
  int rxj = gxj < 56 ? 0 : (gxj < 60 ? 1 : 2);
  int yj_[4], ryj_[4];
#pragma unroll
  for (int n = 0; n < 4; ++n) {
    yj_[n] = 2 * n + (l15 >> 3);
    int gyj = wh * 8 + yj_[n];
    ryj_[n] = gyj < 56 ? 0 : (gyj < 60 ? 1 : 2);
  }
  int rxok_[4], dx8_[4];
#pragma unroll
  for (int i = 0; i < 4; ++i) {
    int xi = (g & 1) * 4 + i;
    int gxi = ww * 8 + xi;
    int rxi = gxi < 56 ? 0 : (gxi < 60 ? 1 : 2);
    rxok_[i] = (rxi == rxj);
    dx8_[i] = (xi - xj + 7) * 8;
  }

  for (int h = 0; h < 8; ++h) {
    const unsigned short* qb = qkv + wbase + h * 32;
    bf16x8 qf[4], kf[4];
#pragma unroll
    for (int m = 0; m < 4; ++m)
      qf[m] = *reinterpret_cast<const bf16x8*>(qb + (size_t)(16 * m + l15) * 768 + g * 8);
#pragma unroll
    for (int n = 0; n < 4; ++n)
      kf[n] = *reinterpret_cast<const bf16x8*>(qb + 256 + (size_t)(16 * n + l15) * 768 + g * 8);

    f32x4 S[4][4];
#pragma unroll
    for (int m = 0; m < 4; ++m)
#pragma unroll
      for (int n = 0; n < 4; ++n) S[m][n] = (f32x4){0.f, 0.f, 0.f, 0.f};
#pragma unroll
    for (int m = 0; m < 4; ++m)
#pragma unroll
      for (int n = 0; n < 4; ++n)
        S[m][n] = __builtin_amdgcn_mfma_f32_16x16x32_bf16(qf[m], kf[n], S[m][n], 0, 0, 0);

    bf16x8 vrow[4];
#pragma unroll
    for (int i2 = 0; i2 < 4; ++i2)
      vrow[i2] = *reinterpret_cast<const bf16x8*>(qb + 512 + (size_t)lane * 768 + i2 * 8);
#pragma unroll
    for (int i2 = 0; i2 < 4; ++i2)
#pragma unroll
      for (int j = 0; j < 8; ++j)
        VT[(i2 * 8 + j) * PS + lane] = (unsigned short)vrow[i2][j];

#pragma unroll
    for (int m = 0; m < 4; ++m) {
      int yi = 2 * m + gh;
      int gyi = wh * 8 + yi;
      int ryi = gyi < 56 ? 0 : (gyi < 60 ? 1 : 2);
      int dy120_[4], rok_[4];
#pragma unroll
      for (int n = 0; n < 4; ++n) {
        dy120_[n] = (yi - yj_[n] + 7) * 120;
        rok_[n] = (ryi == ryj_[n]);
      }
#pragma unroll
      for (int i = 0; i < 4; ++i) {
        float t[4];
#pragma unroll
        for (int n = 0; n < 4; ++n) {
          float bias = rpb[dy120_[n] + dx8_[i] + h];
          float msk = (rok_[n] && rxok_[i]) ? 0.f : -100.f;
          t[n] = fmaf(S[m][n][i], scale, bias + msk);
        }
        float mx = fmaxf(fmaxf(t[0], t[1]), fmaxf(t[2], t[3]));
#pragma unroll
        for (int o = 1; o < 16; o <<= 1) mx = fmaxf(mx, __shfl_xor(mx, o));
        float sm = 0.f;
#pragma unroll
        for (int n = 0; n < 4; ++n) {
          t[n] = __expf(t[n] - mx);
          sm += t[n];
        }
#pragma unroll
        for (int o = 1; o < 16; o <<= 1) sm += __shfl_xor(sm, o);
        float rl = 1.f / sm;
        int rowoff = (16 * m + 4 * g + i) * PS;
#pragma unroll
        for (int n = 0; n < 4; ++n)
          P[rowoff + 16 * n + l15] = f2b(t[n] * rl);
      }
    }

    f32x4 O[4][2];
#pragma unroll
    for (int m = 0; m < 4; ++m)
#pragma unroll
      for (int n2 = 0; n2 < 2; ++n2) O[m][n2] = (f32x4){0.f, 0.f, 0.f, 0.f};
#pragma unroll
    for (int kk = 0; kk < 2; ++kk) {
      bf16x8 pa[4], vb[2];
#pragma unroll
      for (int m = 0; m < 4; ++m)
        pa[m] = *reinterpret_cast<const bf16x8*>(&P[(16 * m + l15) * PS + kk * 32 + g * 8]);
#pragma unroll
      for (int n2 = 0; n2 < 2; ++n2)
        vb[n2] = *reinterpret_cast<const bf16x8*>(&VT[(16 * n2 + l15) * PS + kk * 32 + g * 8]);
#pragma unroll
      for (int m = 0; m < 4; ++m)
#pragma unroll
        for (int n2 = 0; n2 < 2; ++n2)
          O[m][n2] = __builtin_amdgcn_mfma_f32_16x16x32_bf16(pa[m], vb[n2], O[m][n2], 0, 0, 0);
    }

    unsigned short* ob = outb + (size_t)widx * 64 * 256 + h * 32;
#pragma unroll
    for (int m = 0; m < 4; ++m)
#pragma unroll
      for (int n2 = 0; n2 < 2; ++n2)
#pragma unroll
        for (int i = 0; i < 4; ++i)
          ob[(16 * m + 4 * g + i) * 256 + 16 * n2 + l15] = f2b(O[m][n2][i]);
  }
}

// =====================================================================
extern "C" void kernel_launch(void* const* d_in, const int* in_sizes, int n_in,
                              void* d_out, int out_size, void* d_ws,
                              size_t ws_size, hipStream_t stream) {
  const float* x      = (const float*)d_in[0];
  const float* n1w    = (const float*)d_in[1];
  const float* n1b    = (const float*)d_in[2];
  const float* qkvw   = (const float*)d_in[3];
  const float* qkvb   = (const float*)d_in[4];
  const float* rpb    = (const float*)d_in[5];
  const float* projw  = (const float*)d_in[6];
  const float* projb  = (const float*)d_in[7];
  const float* n2w    = (const float*)d_in[8];
  const float* n2b    = (const float*)d_in[9];
  const float* fc1w   = (const float*)d_in[10];
  const float* fc1b   = (const float*)d_in[11];
  const float* fc2w   = (const float*)d_in[12];
  const float* fc2b   = (const float*)d_in[13];
  float* out = (float*)d_out;

  unsigned short* wq = (unsigned short*)d_ws;          // 768*256
  unsigned short* wp = wq + 768 * 256;                 // 256*256
  unsigned short* w1 = wp + 256 * 256;                 // 1024*256
  unsigned short* w2 = w1 + 1024 * 256;                // 256*1024
  unsigned short* bufA = w2 + 256 * 1024;              // 131072*256 bf16
  unsigned short* bufB = bufA + (size_t)kTOK * kC;     // 131072*1024 bf16

  // weights -> bf16
  conv_bf16<<<192, 256, 0, stream>>>(qkvw, wq, 49152);
  conv_bf16<<<64, 256, 0, stream>>>(projw, wp, 16384);
  conv_bf16<<<256, 256, 0, stream>>>(fc1w, w1, 65536);
  conv_bf16<<<256, 256, 0, stream>>>(fc2w, w2, 65536);

  // LN1 + shift + window partition -> bufA (window layout)
  ln1_shift_win<<<kTOK / 4, 256, 0, stream>>>(x, n1w, n1b, bufA);

  // QKV GEMM: [131072,256] x [768,256]^T -> bufB
  gemm_bt2<0, unsigned short><<<(kTOK / 128) * (768 / 256), 512, 0, stream>>>(
      bufA, wq, qkvb, bufB, nullptr, nullptr, nullptr, nullptr, kTOK, 768, kC);

  // attention -> bufA (window layout)
  attn_mfma<<<(kTOK / 64) / 2, 128, 0, stream>>>(bufB, rpb, bufA);

  // proj GEMM fused with residual + LN2:
  //   x1 (original layout, fp32) -> d_out; LN2 (window layout, bf16) -> bufA in place
  gemm_bt2<3, unsigned short><<<(kTOK / 128), 512, 0, stream>>>(
      bufA, wp, projb, bufA, x, out, n2w, n2b, kTOK, kC, kC);

  // FC1 + GELU: [131072,256] x [1024,256]^T -> bufB (window layout)
  gemm_bt2<1, unsigned short><<<(kTOK / 128) * (kMLP / 256), 512, 0, stream>>>(
      bufA, w1, fc1b, bufB, nullptr, nullptr, nullptr, nullptr, kTOK, kMLP, kC);

  // FC2 + residual gather/scatter (window rows -> original layout) -> d_out
  gemm_bt2<4, float><<<(kTOK / 128), 512, 0, stream>>>(
      bufB, w2, fc2b, out, out, nullptr, nullptr, nullptr, kTOK, kC, kMLP);
}